// Round 20
// baseline (157.202 us; speedup 1.0000x reference)
//
#include <hip/hip_runtime.h>
#include <hip/hip_fp16.h>

// Memory_Attention: r = softmax_L(memory @ qs^T) @ qs ; out = (r, memory)
// B=8 L=4096 D=1024 M=512, fp32 in/out.
//
// Round 20: fix round-19 bug. pv's reg-staged A (WRITEA) wrote LDS chunks
// linearly while the frag read XORs chunk with row&7 (that XOR used to be
// baked into P16 by the deleted softmax pass). WRITEA now stores chunk seg
// at position seg ^ (r0&7). Everything else = round 19:
//   softmax pass deleted; qk epilogue emits S16(+mloc,zloc); stats_rows folds
//   stats; pv applies exp(S16 + (mloc-Mrow)) inline in A-staging.
// Pipeline: prep_all -> gemm_qk(S16+mloc+zloc) -> stats_rows -> gemm_pv ->
//           combine_scale.

#define B_ 8
#define L_ 4096
#define D_ 1024
#define M_ 512

typedef _Float16 halfT;
typedef _Float16 half8 __attribute__((ext_vector_type(8)));
typedef _Float16 half4_t __attribute__((ext_vector_type(4)));
typedef float f32x4 __attribute__((ext_vector_type(4)));

// ---- ws layout (bytes) ----
#define OFF_MEM16 0ull
#define SZ_MEM16  (512ull*1024*2)             //  1,048,576
#define OFF_QS16  (OFF_MEM16 + SZ_MEM16)
#define SZ_QS16   (8ull*4096*1024*2)          // 67,108,864
#define OFF_S     (OFF_QS16 + SZ_QS16)
#define SZ_S      (8ull*512*4096*4)           // 67MB slot (S16 uses 33.5, live thru pv)
#define OFF_RP    (OFF_S + SZ_S)              // rp16: 33,554,432
#define SZ_RP     (8ull*512*4096*2)
#define OFF_INVL  (OFF_RP + SZ_RP)
#define SZ_INVL   (8ull*512*4)
#define OFF_MLOC  (OFF_INVL + SZ_INVL)
#define SZ_MLOC   (8ull*16*512*4)             // 262,144
#define OFF_ZLOC  (OFF_MLOC + SZ_MLOC)
#define SZ_ZLOC   (8ull*16*512*4)
#define OFF_MROW  (OFF_ZLOC + SZ_ZLOC)
#define SZ_MROW   (8ull*512*4)
#define WS_NEED   (OFF_MROW + SZ_MROW)        // ~169.5 MB (ws known >= 202 MB)

#define SWZ(n) ((((n)&7) ^ (((n)>>5)&7)))

__device__ __forceinline__ void gload_lds16(const halfT* g, halfT* l) {
  __builtin_amdgcn_global_load_lds(
      (const __attribute__((address_space(1))) unsigned int*)(const void*)g,
      (__attribute__((address_space(3))) unsigned int*)l, 16, 0, 0);
}

// ---------------- prep: streaming fp32 -> fp16, row-chunk pre-swizzle ----------------
__global__ __launch_bounds__(256)
void prep_all(const float* __restrict__ qs, const float* __restrict__ mem,
              halfT* __restrict__ q16, halfT* __restrict__ mem16) {
  int bid = blockIdx.x;
  int tid = threadIdx.x;
  if (bid < 2048) {
    size_t base = (size_t)bid*256 + tid;
    #pragma unroll
    for (int it = 0; it < 8; ++it) {
      size_t i8 = base + (size_t)it*524288;   // half8 index (4,194,304 total)
      size_t row = i8 >> 7;
      int c = (int)(i8 & 127);
      int kt = c >> 3, g = c & 7;
      const float* src = qs + i8*8;
      f32x4 x0 = *(const f32x4*)&src[0];
      f32x4 x1 = *(const f32x4*)&src[4];
      half8 h;
      #pragma unroll
      for (int j = 0; j < 4; ++j) { h[j] = (halfT)x0[j]; h[4+j] = (halfT)x1[j]; }
      *(half8*)&q16[row*1024 + kt*64 + ((g ^ ((int)row & 7)) << 3)] = h;
    }
  } else {
    int i8 = (bid - 2048)*256 + tid;          // 65536 half8 exact
    int row = i8 >> 7, c = i8 & 127;
    int kt = c >> 3, g = c & 7;
    const float* src = mem + (size_t)i8*8;
    f32x4 x0 = *(const f32x4*)src;
    f32x4 x1 = *(const f32x4*)(src + 4);
    half8 h;
    #pragma unroll
    for (int j = 0; j < 4; ++j) { h[j] = (halfT)x0[j]; h[4+j] = (halfT)x1[j]; }
    *(half8*)&mem16[(size_t)row*1024 + kt*64 + ((g ^ (row & 7)) << 3)] = h;
  }
}

// ---------------- gemm_qk: S16 = mem16 @ qs16^T - m_loc ; m_loc, zloc stats ----------------
__global__ __launch_bounds__(512, 2)
void gemm_qk(const halfT* __restrict__ mem16, const halfT* __restrict__ qs16,
             halfT* __restrict__ S16, float* __restrict__ mloc,
             float* __restrict__ zloc)
{
  __shared__ __attribute__((aligned(16))) halfT At[2][256*64];   // 64 KB
  __shared__ __attribute__((aligned(16))) halfT Bt[2][256*64];   // 64 KB

  int bid = blockIdx.x;                      // 256
  int swz = (bid & 7)*32 + (bid >> 3);       // XCD-contiguous
  int b   = swz >> 5;                        // one b per XCD
  int rem = swz & 31;
  int nt  = rem >> 1;
  int mt  = rem & 1;

  int tid = threadIdx.x;
  int w = tid >> 6, lane = tid & 63, lg = lane >> 4, li = lane & 15;
  int wm = w >> 2, wn = w & 3;
  int sl = li & 7;
  int rA = tid >> 3;
  int cA = (tid & 7)*8;

  const halfT* Ab = mem16 + (size_t)mt*256*1024;
  const halfT* Bb = qs16 + ((size_t)b*L_ + nt*256)*D_;

  f32x4 acc[8][4];
  #pragma unroll
  for (int i=0;i<8;++i)
    #pragma unroll
    for (int j=0;j<4;++j) acc[i][j] = (f32x4){0.f,0.f,0.f,0.f};

#define STAGE_QK(nb_, kt_)                                                     \
  do {                                                                         \
    const halfT* a0 = Ab + (size_t)(kt_)*64 + cA;                              \
    const halfT* b0 = Bb + (size_t)(kt_)*64 + cA;                              \
    _Pragma("unroll")                                                          \
    for (int j = 0; j < 4; ++j) {                                              \
      int r = rA + j*64;                                                       \
      gload_lds16(a0 + (size_t)r*1024, &At[nb_][(tid + j*512)*8]);             \
      gload_lds16(b0 + (size_t)r*1024, &Bt[nb_][(tid + j*512)*8]);             \
    }                                                                          \
  } while (0)

#define COMPUTE_QK(nb_)                                                        \
  do {                                                                         \
    _Pragma("unroll")                                                          \
    for (int ksub = 0; ksub < 2; ++ksub) {                                     \
      int gx = ((ksub*4 + lg) ^ sl) << 3;                                      \
      half8 Af[8], Bf[4];                                                      \
      _Pragma("unroll")                                                        \
      for (int mf = 0; mf < 8; ++mf)                                           \
        Af[mf] = *(const half8*)&At[nb_][(wm*128 + mf*16 + li)*64 + gx];       \
      _Pragma("unroll")                                                        \
      for (int nf = 0; nf < 4; ++nf)                                           \
        Bf[nf] = *(const half8*)&Bt[nb_][(wn*64 + nf*16 + li)*64 + gx];        \
      _Pragma("unroll")                                                        \
      for (int mf = 0; mf < 8; ++mf)                                           \
        _Pragma("unroll")                                                      \
        for (int nf = 0; nf < 4; ++nf)                                         \
          acc[mf][nf] = __builtin_amdgcn_mfma_f32_16x16x32_f16(Af[mf], Bf[nf], acc[mf][nf], 0,0,0); \
    }                                                                          \
  } while (0)

  STAGE_QK(0, 0);
  STAGE_QK(1, 1);
  asm volatile("s_waitcnt vmcnt(8)" ::: "memory");
  __builtin_amdgcn_sched_barrier(0);
  __builtin_amdgcn_s_barrier();

  for (int kt = 0; kt < 16; ++kt) {
    COMPUTE_QK(kt & 1);
    __builtin_amdgcn_s_barrier();            // B2
    if (kt + 2 < 16) {
      STAGE_QK(kt & 1, kt + 2);
      asm volatile("s_waitcnt vmcnt(8) lgkmcnt(0)" ::: "memory");
    } else {
      asm volatile("s_waitcnt vmcnt(0) lgkmcnt(0)" ::: "memory");
    }
    __builtin_amdgcn_sched_barrier(0);
    __builtin_amdgcn_s_barrier();            // B1
  }
#undef STAGE_QK
#undef COMPUTE_QK

  // ---- epilogue: block-local row max + exp-sum, stats, S16 permuted write ----
  float* red  = (float*)&At[0][0];           // 1024 f32
  float* red2 = red + 1024;                  // 1024 f32
  float m4[8][4];
  #pragma unroll
  for (int mf = 0; mf < 8; ++mf)
    #pragma unroll
    for (int r = 0; r < 4; ++r) {
      float vmax = fmaxf(fmaxf(acc[mf][0][r], acc[mf][1][r]),
                         fmaxf(acc[mf][2][r], acc[mf][3][r]));
      #pragma unroll
      for (int off = 1; off < 16; off <<= 1) vmax = fmaxf(vmax, __shfl_xor(vmax, off));
      if (li == 0) red[w*128 + mf*16 + lg*4 + r] = vmax;
    }
  __syncthreads();
  #pragma unroll
  for (int mf = 0; mf < 8; ++mf)
    #pragma unroll
    for (int r = 0; r < 4; ++r) {
      int idx = mf*16 + lg*4 + r;
      m4[mf][r] = fmaxf(fmaxf(red[(wm*4+0)*128 + idx], red[(wm*4+1)*128 + idx]),
                        fmaxf(red[(wm*4+2)*128 + idx], red[(wm*4+3)*128 + idx]));
    }
  #pragma unroll
  for (int mf = 0; mf < 8; ++mf)
    #pragma unroll
    for (int r = 0; r < 4; ++r) {
      float e = 0.f;
      #pragma unroll
      for (int nf = 0; nf < 4; ++nf) e += __expf(acc[mf][nf][r] - m4[mf][r]);
      #pragma unroll
      for (int off = 1; off < 16; off <<= 1) e += __shfl_xor(e, off);
      if (li == 0) red2[w*128 + mf*16 + lg*4 + r] = e;
    }
  __syncthreads();
  if (wn == 0 && li == 0) {                  // one writer per row
    #pragma unroll
    for (int mf = 0; mf < 8; ++mf)
      #pragma unroll
      for (int r = 0; r < 4; ++r) {
        int idx = mf*16 + lg*4 + r;
        int m = mt*256 + wm*128 + idx;
        float z = red2[(wm*4+0)*128 + idx] + red2[(wm*4+1)*128 + idx]
                + red2[(wm*4+2)*128 + idx] + red2[(wm*4+3)*128 + idx];
        mloc[((size_t)b*16 + nt)*M_ + m] = m4[mf][r];
        zloc[((size_t)b*16 + nt)*M_ + m] = z;
      }
  }
  halfT* Cb = S16 + (size_t)b*M_*L_;
  int cpb = nt*256 + wn*64 + li*4;
  #pragma unroll
  for (int mf = 0; mf < 8; ++mf) {
    #pragma unroll
    for (int r = 0; r < 4; ++r) {
      int row = mt*256 + wm*128 + mf*16 + lg*4 + r;
      half4_t hv;
      #pragma unroll
      for (int nf = 0; nf < 4; ++nf) hv[nf] = (halfT)(acc[mf][nf][r] - m4[mf][r]);
      *(half4_t*)&Cb[(size_t)row*L_ + cpb] = hv;
    }
  }
}

// ---------------- stats: Mrow = max_nt mloc ; invl = 1/sum zloc*exp(mloc-Mrow) ----------------
__global__ __launch_bounds__(256)
void stats_rows(const float* __restrict__ mloc, const float* __restrict__ zloc,
                float* __restrict__ Mrow, float* __restrict__ invl)
{
  int row = blockIdx.x*256 + threadIdx.x;    // 4096
  int b = row >> 9, m = row & 511;
  const float* mp = mloc + (size_t)b*16*M_ + m;
  const float* zp = zloc + (size_t)b*16*M_ + m;
  float ml[16], M = -3.0e38f;
  #pragma unroll
  for (int t = 0; t < 16; ++t) { ml[t] = mp[(size_t)t*M_]; M = fmaxf(M, ml[t]); }
  float Z = 0.f;
  #pragma unroll
  for (int t = 0; t < 16; ++t) Z += zp[(size_t)t*M_] * __expf(ml[t] - M);
  Mrow[row] = M;
  invl[row] = 1.0f / Z;
}

// ---------------- gemm_pv: rp16[ks] = exp(S16+di) @ qs16 (K-chunk ks) ----------------
// A = exp inline in reg-staged A-staging; WRITEA stores chunk seg at position
// seg ^ (r0&7) so the frag read's ^ (li&7) finds the right data (r20 fix).
__global__ __launch_bounds__(512, 2)
void gemm_pv(const halfT* __restrict__ S16, const halfT* __restrict__ qs16,
             const float* __restrict__ mloc, const float* __restrict__ Mrow,
             halfT* __restrict__ rp16)
{
  __shared__ __attribute__((aligned(16))) halfT At[2][256*64];   // 64 KB
  __shared__ __attribute__((aligned(16))) halfT Bt[2][256*64];   // 64 KB

  int bid = blockIdx.x;                      // 256
  int swz = (bid & 7)*32 + (bid >> 3);
  int ks  = swz >> 6;                        // 0..3
  int rem = swz & 63;
  int b   = rem >> 3;
  int nt  = (rem >> 1) & 3;
  int mt  = rem & 1;

  int tid = threadIdx.x;
  int w = tid >> 6, lane = tid & 63, lg = lane >> 4, li = lane & 15;
  int wm = w >> 2, wn = w & 3;
  int sl = li & 7;

  const halfT* Ab = S16 + (size_t)b*M_*L_ + (size_t)mt*256*L_ + ks*1024;
  const halfT* Bb = qs16 + ((size_t)b*L_ + ks*1024)*D_ + nt*256;
  int krow = tid >> 3;                       // 0..63
  int seg  = tid & 7;
  int pinv = ((krow & 3) << 4) | (krow >> 2);
  int rs   = pinv & 7;
  int r0   = tid >> 3;                       // A rows r0 + j*64
  int rsA  = r0 & 7;                         // row&7 (constant: rows step by 64)

  // preload per-row shifts dl[j][t] = mloc[b][ks*4+t][m] - Mrow[m]
  float dl[4][4];
  #pragma unroll
  for (int j = 0; j < 4; ++j) {
    int m = mt*256 + r0 + j*64;
    float Mr = Mrow[b*512 + m];
    #pragma unroll
    for (int t = 0; t < 4; ++t)
      dl[j][t] = mloc[((size_t)b*16 + ks*4 + t)*M_ + m] - Mr;
  }

  f32x4 acc[8][4];
  #pragma unroll
  for (int i=0;i<8;++i)
    #pragma unroll
    for (int j=0;j<4;++j) acc[i][j] = (f32x4){0.f,0.f,0.f,0.f};

  half8 ax[4], hx[4];

#define GLOADA_PV(kt_)                                                         \
  do {                                                                         \
    _Pragma("unroll")                                                          \
    for (int j = 0; j < 4; ++j)                                                \
      ax[j] = *(const half8*)(Ab + (size_t)(r0 + j*64)*L_ + (kt_)*64 + seg*8); \
  } while (0)

#define WRITEA_PV(nb_, kt_)                                                    \
  do {                                                                         \
    int t_ = (kt_) >> 2;                                                       \
    _Pragma("unroll")                                                          \
    for (int j = 0; j < 4; ++j) {                                              \
      half8 h;                                                                 \
      _Pragma("unroll")                                                        \
      for (int e = 0; e < 8; ++e)                                              \
        h[e] = (halfT)__expf((float)ax[j][e] + dl[j][t_]);                     \
      *(half8*)&At[nb_][(r0 + j*64)*64 + ((seg ^ rsA) << 3)] = h;              \
    }                                                                          \
  } while (0)

#define GLOADB_PV(kt_)                                                         \
  do {                                                                         \
    const halfT* rowp = Bb + (size_t)((kt_)*64 + pinv)*D_ + (seg >> 1)*64;     \
    _Pragma("unroll")                                                          \
    for (int j = 0; j < 4; ++j)                                                \
      hx[j] = *(const half8*)(rowp + ((((seg & 1)*4 + j) ^ rs) << 3));         \
  } while (0)

#define WRITEB_PV(nb_)                                                         \
  do {                                                                         \
    _Pragma("unroll")                                                          \
    for (int i = 0; i < 32; ++i) {                                             \
      int n_ = seg*32 + i;                                                     \
      Bt[nb_][n_*64 + ((((krow >> 3) ^ SWZ(n_)) << 3)) + (krow & 7)] =         \
          hx[i >> 3][i & 7];                                                   \
    }                                                                          \
  } while (0)

#define COMPUTE_PV(nb_)                                                        \
  do {                                                                         \
    _Pragma("unroll")                                                          \
    for (int ksub = 0; ksub < 2; ++ksub) {                                     \
      int gx = ((ksub*4 + lg) ^ sl) << 3;                                      \
      half8 Af[8], Bf[4];                                                      \
      _Pragma("unroll")                                                        \
      for (int mf = 0; mf < 8; ++mf)                                           \
        Af[mf] = *(const half8*)&At[nb_][(wm*128 + mf*16 + li)*64 + gx];       \
      _Pragma("unroll")                                                        \
      for (int nf = 0; nf < 4; ++nf) {                                         \
        int n_ = wn*64 + nf*16 + li;                                           \
        Bf[nf] = *(const half8*)&Bt[nb_][n_*64 + (((ksub*4 + lg) ^ SWZ(n_)) << 3)]; \
      }                                                                        \
      _Pragma("unroll")                                                        \
      for (int mf = 0; mf < 8; ++mf)                                           \
        _Pragma("unroll")                                                      \
        for (int nf = 0; nf < 4; ++nf)                                         \
          acc[mf][nf] = __builtin_amdgcn_mfma_f32_16x16x32_f16(Af[mf], Bf[nf], acc[mf][nf], 0,0,0); \
    }                                                                          \
  } while (0)

  // Prologue: tile 0 staged; tile-1 loads in flight.
  GLOADA_PV(0); GLOADB_PV(0);
  WRITEA_PV(0, 0); WRITEB_PV(0);             // data-dep waits on ax/hx(0)
  GLOADA_PV(1); GLOADB_PV(1);
  asm volatile("s_waitcnt lgkmcnt(0)" ::: "memory");
  __builtin_amdgcn_sched_barrier(0);
  __builtin_amdgcn_s_barrier();

  for (int kt = 0; kt < 16; ++kt) {
    int nb = kt & 1;
    COMPUTE_PV(nb);
    __builtin_amdgcn_s_barrier();            // B2: reads of tile kt done
    if (kt + 1 < 16) { WRITEA_PV(nb ^ 1, kt + 1); WRITEB_PV(nb ^ 1); }
    if (kt + 2 < 16) { GLOADA_PV(kt + 2); GLOADB_PV(kt + 2); }
    asm volatile("s_waitcnt lgkmcnt(0)" ::: "memory");
    __builtin_amdgcn_sched_barrier(0);
    __builtin_amdgcn_s_barrier();            // B1: tile kt+1 in LDS
  }
#undef GLOADA_PV
#undef WRITEA_PV
#undef GLOADB_PV
#undef WRITEB_PV
#undef COMPUTE_PV

  halfT* Cb = rp16 + (size_t)ks*((size_t)B_*M_*D_) + (size_t)b*M_*D_;
  int cpbase = nt*256 + wn*64 + li*4;
  #pragma unroll
  for (int mf = 0; mf < 8; ++mf) {
    #pragma unroll
    for (int r = 0; r < 4; ++r) {
      int row = mt*256 + wm*128 + mf*16 + lg*4 + r;
      half4_t hv;
      #pragma unroll
      for (int nf = 0; nf < 4; ++nf) hv[nf] = (halfT)acc[mf][nf][r];
      *(half4_t*)&Cb[(size_t)row*D_ + cpbase] = hv;
    }
  }
}

// ---------------- combine: out = invl * sum_ks rp16[ks] (permuted cols) ----------------
__global__ __launch_bounds__(256)
void combine_scale(const halfT* __restrict__ rp16, const float* __restrict__ invl,
                   float* __restrict__ out)
{
  int bm = blockIdx.x;                     // 0..4095
  int t = threadIdx.x;
  size_t off = (size_t)bm*D_ + t*4;
  f32x4 v = (f32x4){0.f,0.f,0.f,0.f};
  #pragma unroll
  for (int s = 0; s < 4; ++s) {
    half4_t h = *(const half4_t*)&rp16[(size_t)s*((size_t)B_*M_*D_) + off];
    #pragma unroll
    for (int j = 0; j < 4; ++j) v[j] += (float)h[j];
  }
  float sc = invl[bm];
  v *= sc;
  int W = (t >> 4) << 6;
  float* ob = out + (size_t)bm*D_;
  #pragma unroll
  for (int j = 0; j < 4; ++j)
    ob[W + j*16 + (t & 15)] = v[j];
}

// ---------------- fallback (tiny ws): correct, slow fp32 ----------------
__global__ void fallback_kernel(const float* __restrict__ qs,
                                const float* __restrict__ mem,
                                float* __restrict__ out)
{
  __shared__ float w_lds[4][4096];
  __shared__ float mem_s[4][1024];
  __shared__ float redb[256];
  int blk = blockIdx.x;
  int b = blk >> 7;
  int m0 = (blk & 127)*4;
  int tid = threadIdx.x;

  for (int i = tid; i < 4*1024; i += 256)
    mem_s[i>>10][i&1023] = mem[(size_t)(m0 + (i>>10))*D_ + (i&1023)];
  __syncthreads();

  float mx[4] = {-3e38f,-3e38f,-3e38f,-3e38f};
  for (int l = tid; l < L_; l += 256) {
    const float* qp = qs + ((size_t)b*L_ + l)*D_;
    float dot[4] = {0,0,0,0};
    for (int dd = 0; dd < D_; dd += 4) {
      f32x4 qv = *(const f32x4*)(qp + dd);
      #pragma unroll
      for (int mi=0; mi<4; ++mi)
        dot[mi] += qv[0]*mem_s[mi][dd] + qv[1]*mem_s[mi][dd+1]
                 + qv[2]*mem_s[mi][dd+2] + qv[3]*mem_s[mi][dd+3];
    }
    #pragma unroll
    for (int mi=0; mi<4; ++mi) { w_lds[mi][l] = dot[mi]; mx[mi] = fmaxf(mx[mi], dot[mi]); }
  }
  float Mv[4], Zv[4];
  for (int mi=0; mi<4; ++mi) {
    redb[tid] = mx[mi]; __syncthreads();
    for (int s=128; s>0; s>>=1) { if (tid<s) redb[tid]=fmaxf(redb[tid],redb[tid+s]); __syncthreads(); }
    Mv[mi] = redb[0]; __syncthreads();
  }
  float sm[4] = {0,0,0,0};
  for (int l = tid; l < L_; l += 256)
    #pragma unroll
    for (int mi=0; mi<4; ++mi) {
      float wv = __expf(w_lds[mi][l] - Mv[mi]);
      w_lds[mi][l] = wv; sm[mi] += wv;
    }
  for (int mi=0; mi<4; ++mi) {
    redb[tid] = sm[mi]; __syncthreads();
    for (int s=128; s>0; s>>=1) { if (tid<s) redb[tid]+=redb[tid+s]; __syncthreads(); }
    Zv[mi] = redb[0]; __syncthreads();
  }
  int d0 = tid*4;
  f32x4 a[4];
  #pragma unroll
  for (int mi=0;mi<4;++mi) a[mi] = (f32x4){0,0,0,0};
  for (int l = 0; l < L_; ++l) {
    f32x4 qv = *(const f32x4*)(qs + ((size_t)b*L_ + l)*D_ + d0);
    #pragma unroll
    for (int mi=0; mi<4; ++mi) a[mi] += qv * w_lds[mi][l];
  }
  #pragma unroll
  for (int mi=0; mi<4; ++mi) {
    float invz = 1.f/Zv[mi];
    #pragma unroll
    for (int c=0; c<4; ++c)
      out[((size_t)b*M_ + m0 + mi)*D_ + d0 + c] = a[mi][c]*invz;
  }
}

extern "C" void kernel_launch(void* const* d_in, const int* in_sizes, int n_in,
                              void* d_out, int out_size, void* d_ws, size_t ws_size,
                              hipStream_t stream) {
  const float* qs  = (const float*)d_in[0];
  const float* mem = (const float*)d_in[1];
  float* out = (float*)d_out;

  // tuple output: r [8*512*1024] then memory [512*1024]
  hipMemcpyAsync(out + (size_t)B_*M_*D_, mem, (size_t)M_*D_*sizeof(float),
                 hipMemcpyDeviceToDevice, stream);

  if (ws_size >= (size_t)WS_NEED) {
    char* base = (char*)d_ws;
    halfT* mem16 = (halfT*)(base + OFF_MEM16);
    halfT* qs16  = (halfT*)(base + OFF_QS16);
    halfT* S16   = (halfT*)(base + OFF_S);
    halfT* rp16  = (halfT*)(base + OFF_RP);
    float* invl  = (float*)(base + OFF_INVL);
    float* mloc  = (float*)(base + OFF_MLOC);
    float* zloc  = (float*)(base + OFF_ZLOC);
    float* Mrow  = (float*)(base + OFF_MROW);

    prep_all<<<2304, 256, 0, stream>>>(qs, mem, qs16, mem16);
    gemm_qk<<<256, 512, 0, stream>>>(mem16, qs16, S16, mloc, zloc);
    stats_rows<<<16, 256, 0, stream>>>(mloc, zloc, Mrow, invl);
    gemm_pv<<<256, 512, 0, stream>>>(S16, qs16, mloc, Mrow, rp16);
    combine_scale<<<4096, 256, 0, stream>>>(rp16, invl, out);
  } else {
    fallback_kernel<<<1024, 256, 0, stream>>>(qs, mem, out);
  }
}

// Round 21
// 143.877 us; speedup vs baseline: 1.0926x; 1.0926x over previous
//
#include <hip/hip_runtime.h>
#include <hip/hip_fp16.h>

// Memory_Attention: r = softmax_L(memory @ qs^T) @ qs ; out = (r, memory)
// B=8 L=4096 D=1024 M=512, fp32 in/out.
//
// Round 21: REVERT to round 17 (best verified: 145.9us). Round 19/20's
// softmax-fusion was net-negative (-10us pass time, +20us pv: reg-staged A
// with inline exp loses to gload_lds of pre-baked P16). Ledger on r17 base:
// r18 frag-hoist neutral, T5 setprio negative, fusion negative.
//   prep_all: fp32->fp16 + row-chunk pre-swizzle (qs16, mem16)
//   gemm_qk : 256^2, BK=64, 8 waves, dbuf, counted-vmcnt; epilogue computes
//             block-local row max m_loc, stores S16 = S - m_loc (fp16,
//             lane-permuted cols) + m_loc stats.
//   softmax : 1 row/wave; M = max_nt m_loc; P16 = exp(S16 + (m_loc-M)),
//             pre-swizzled for pv's gload_lds; invl = 1/sum.
//   gemm_pv : split-K x4; A=P16 gload_lds; B=qs16 reg-staged transpose
//             (pinv k-permutation compensation); rp16 fp16 lane-permuted.
//   combine : out = invl * sum_ks rp16.

#define B_ 8
#define L_ 4096
#define D_ 1024
#define M_ 512

typedef _Float16 halfT;
typedef _Float16 half8 __attribute__((ext_vector_type(8)));
typedef _Float16 half4_t __attribute__((ext_vector_type(4)));
typedef float f32x4 __attribute__((ext_vector_type(4)));

// ---- ws layout (bytes) ----
#define OFF_MEM16 0ull
#define SZ_MEM16  (512ull*1024*2)             //  1,048,576
#define OFF_QS16  (OFF_MEM16 + SZ_MEM16)
#define SZ_QS16   (8ull*4096*1024*2)          // 67,108,864
#define OFF_S     (OFF_QS16 + SZ_QS16)
#define SZ_S      (8ull*512*4096*4)           // slot kept at 67MB (S16 uses 33.5)
#define OFF_P16   (OFF_S + SZ_S)
#define SZ_P16    (8ull*512*4096*2)           // 33,554,432
#define OFF_INVL  (OFF_P16 + SZ_P16)
#define SZ_INVL   (8ull*512*4)
#define OFF_MLOC  (OFF_INVL + SZ_INVL)
#define SZ_MLOC   (8ull*16*512*4)             // 262,144
#define WS_NEED   (OFF_MLOC + SZ_MLOC)        // ~169 MB (ws known >= 202 MB)
#define OFF_RP    OFF_S                       // overlay: S16 dead after softmax

#define SWZ(n) ((((n)&7) ^ (((n)>>5)&7)))

__device__ __forceinline__ void gload_lds16(const halfT* g, halfT* l) {
  __builtin_amdgcn_global_load_lds(
      (const __attribute__((address_space(1))) unsigned int*)(const void*)g,
      (__attribute__((address_space(3))) unsigned int*)l, 16, 0, 0);
}

// ---------------- prep: streaming fp32 -> fp16, row-chunk pre-swizzle ----------------
// Row-major [R][1024]; within each 64-half window, chunk g lives at g ^ (row&7).
__global__ __launch_bounds__(256)
void prep_all(const float* __restrict__ qs, const float* __restrict__ mem,
              halfT* __restrict__ q16, halfT* __restrict__ mem16) {
  int bid = blockIdx.x;
  int tid = threadIdx.x;
  if (bid < 2048) {
    size_t base = (size_t)bid*256 + tid;
    #pragma unroll
    for (int it = 0; it < 8; ++it) {
      size_t i8 = base + (size_t)it*524288;   // half8 index (4,194,304 total)
      size_t row = i8 >> 7;
      int c = (int)(i8 & 127);
      int kt = c >> 3, g = c & 7;
      const float* src = qs + i8*8;
      f32x4 x0 = *(const f32x4*)&src[0];
      f32x4 x1 = *(const f32x4*)&src[4];
      half8 h;
      #pragma unroll
      for (int j = 0; j < 4; ++j) { h[j] = (halfT)x0[j]; h[4+j] = (halfT)x1[j]; }
      *(half8*)&q16[row*1024 + kt*64 + ((g ^ ((int)row & 7)) << 3)] = h;
    }
  } else {
    int i8 = (bid - 2048)*256 + tid;          // 65536 half8 exact
    int row = i8 >> 7, c = i8 & 127;
    int kt = c >> 3, g = c & 7;
    const float* src = mem + (size_t)i8*8;
    f32x4 x0 = *(const f32x4*)src;
    f32x4 x1 = *(const f32x4*)(src + 4);
    half8 h;
    #pragma unroll
    for (int j = 0; j < 4; ++j) { h[j] = (halfT)x0[j]; h[4+j] = (halfT)x1[j]; }
    *(half8*)&mem16[(size_t)row*1024 + kt*64 + ((g ^ (row & 7)) << 3)] = h;
  }
}

// ---------------- gemm_qk: S16[b][512][4096'] = mem16 @ qs16^T - m_loc ----------------
// 256^2 tile, BK=64, 8 waves, dbuf + counted-vmcnt pipeline. Per b: MT=2, NT=16.
__global__ __launch_bounds__(512, 2)
void gemm_qk(const halfT* __restrict__ mem16, const halfT* __restrict__ qs16,
             halfT* __restrict__ S16, float* __restrict__ mloc)
{
  __shared__ __attribute__((aligned(16))) halfT At[2][256*64];   // 64 KB
  __shared__ __attribute__((aligned(16))) halfT Bt[2][256*64];   // 64 KB

  int bid = blockIdx.x;                      // 256
  int swz = (bid & 7)*32 + (bid >> 3);       // XCD-contiguous
  int b   = swz >> 5;                        // one b per XCD
  int rem = swz & 31;
  int nt  = rem >> 1;
  int mt  = rem & 1;

  int tid = threadIdx.x;
  int w = tid >> 6, lane = tid & 63, lg = lane >> 4, li = lane & 15;
  int wm = w >> 2, wn = w & 3;
  int sl = li & 7;                           // row&7 of every frag row this lane reads
  int rA = tid >> 3;
  int cA = (tid & 7)*8;

  const halfT* Ab = mem16 + (size_t)mt*256*1024;
  const halfT* Bb = qs16 + ((size_t)b*L_ + nt*256)*D_;

  f32x4 acc[8][4];
  #pragma unroll
  for (int i=0;i<8;++i)
    #pragma unroll
    for (int j=0;j<4;++j) acc[i][j] = (f32x4){0.f,0.f,0.f,0.f};

// 8 gload_lds per thread = 8 vm-instructions per wave per tile (vmcnt unit).
#define STAGE_QK(nb_, kt_)                                                     \
  do {                                                                         \
    const halfT* a0 = Ab + (size_t)(kt_)*64 + cA;                              \
    const halfT* b0 = Bb + (size_t)(kt_)*64 + cA;                              \
    _Pragma("unroll")                                                          \
    for (int j = 0; j < 4; ++j) {                                              \
      int r = rA + j*64;                                                       \
      gload_lds16(a0 + (size_t)r*1024, &At[nb_][(tid + j*512)*8]);             \
      gload_lds16(b0 + (size_t)r*1024, &Bt[nb_][(tid + j*512)*8]);             \
    }                                                                          \
  } while (0)

#define COMPUTE_QK(nb_)                                                        \
  do {                                                                         \
    _Pragma("unroll")                                                          \
    for (int ksub = 0; ksub < 2; ++ksub) {                                     \
      int gx = ((ksub*4 + lg) ^ sl) << 3;                                      \
      half8 Af[8], Bf[4];                                                      \
      _Pragma("unroll")                                                        \
      for (int mf = 0; mf < 8; ++mf)                                           \
        Af[mf] = *(const half8*)&At[nb_][(wm*128 + mf*16 + li)*64 + gx];       \
      _Pragma("unroll")                                                        \
      for (int nf = 0; nf < 4; ++nf)                                           \
        Bf[nf] = *(const half8*)&Bt[nb_][(wn*64 + nf*16 + li)*64 + gx];        \
      _Pragma("unroll")                                                        \
      for (int mf = 0; mf < 8; ++mf)                                           \
        _Pragma("unroll")                                                      \
        for (int nf = 0; nf < 4; ++nf)                                         \
          acc[mf][nf] = __builtin_amdgcn_mfma_f32_16x16x32_f16(Af[mf], Bf[nf], acc[mf][nf], 0,0,0); \
    }                                                                          \
  } while (0)

  // Prologue: tiles 0 and 1 in flight; wait only tile 0 (vmcnt(8)).
  STAGE_QK(0, 0);
  STAGE_QK(1, 1);
  asm volatile("s_waitcnt vmcnt(8)" ::: "memory");
  __builtin_amdgcn_sched_barrier(0);
  __builtin_amdgcn_s_barrier();

  for (int kt = 0; kt < 16; ++kt) {
    COMPUTE_QK(kt & 1);
    __builtin_amdgcn_s_barrier();            // B2: all reads of buf[kt&1] done
    if (kt + 2 < 16) {
      STAGE_QK(kt & 1, kt + 2);              // overwrite just-freed buffer
      asm volatile("s_waitcnt vmcnt(8) lgkmcnt(0)" ::: "memory");
    } else {
      asm volatile("s_waitcnt vmcnt(0) lgkmcnt(0)" ::: "memory");
    }
    __builtin_amdgcn_sched_barrier(0);
    __builtin_amdgcn_s_barrier();            // B1: tile kt+1 fully in LDS
  }
#undef STAGE_QK
#undef COMPUTE_QK

  // ---- epilogue: block-local row max (256 cols), stats, S16 permuted write ----
  float* red = (float*)&At[0][0];            // 8*128 f32 scratch (LDS free now)
  float m4[8][4];
  #pragma unroll
  for (int mf = 0; mf < 8; ++mf)
    #pragma unroll
    for (int r = 0; r < 4; ++r) {
      float vmax = fmaxf(fmaxf(acc[mf][0][r], acc[mf][1][r]),
                         fmaxf(acc[mf][2][r], acc[mf][3][r]));
      #pragma unroll
      for (int off = 1; off < 16; off <<= 1) vmax = fmaxf(vmax, __shfl_xor(vmax, off));
      if (li == 0) red[w*128 + mf*16 + lg*4 + r] = vmax;
    }
  __syncthreads();
  #pragma unroll
  for (int mf = 0; mf < 8; ++mf)
    #pragma unroll
    for (int r = 0; r < 4; ++r) {
      int idx = mf*16 + lg*4 + r;
      m4[mf][r] = fmaxf(fmaxf(red[(wm*4+0)*128 + idx], red[(wm*4+1)*128 + idx]),
                        fmaxf(red[(wm*4+2)*128 + idx], red[(wm*4+3)*128 + idx]));
    }
  if (wn == 0 && li == 0) {                  // one writer per row (waves 0 and 4)
    #pragma unroll
    for (int mf = 0; mf < 8; ++mf)
      #pragma unroll
      for (int r = 0; r < 4; ++r) {
        int m = mt*256 + wm*128 + mf*16 + lg*4 + r;
        mloc[((size_t)b*16 + nt)*M_ + m] = m4[mf][r];
      }
  }
  halfT* Cb = S16 + (size_t)b*M_*L_;
  int cpb = nt*256 + wn*64 + li*4;           // permuted col base for this lane
  #pragma unroll
  for (int mf = 0; mf < 8; ++mf) {
    #pragma unroll
    for (int r = 0; r < 4; ++r) {
      int row = mt*256 + wm*128 + mf*16 + lg*4 + r;
      half4_t hv;
      #pragma unroll
      for (int nf = 0; nf < 4; ++nf) hv[nf] = (halfT)(acc[mf][nf][r] - m4[mf][r]);
      *(half4_t*)&Cb[(size_t)row*L_ + cpb] = hv;
    }
  }
}

// ---------------- gemm_pv: rp16[ks][b][512][1024'] = P16 @ qs16 (K-chunk ks) ----------------
// A=P16 (pre-swizzled, permuted k-cols) via gload_lds; B=qs16 reg-staged
// in-LDS transpose with k-permutation compensation: Bt k-position krow holds
// qs16 row pinv(krow) = ((krow&3)<<4)|(krow>>2). Output fp16 lane-permuted.
__global__ __launch_bounds__(512, 2)
void gemm_pv(const halfT* __restrict__ P16, const halfT* __restrict__ qs16,
             halfT* __restrict__ rp16)
{
  __shared__ __attribute__((aligned(16))) halfT At[2][256*64];   // 64 KB
  __shared__ __attribute__((aligned(16))) halfT Bt[2][256*64];   // 64 KB

  int bid = blockIdx.x;                      // 256
  int swz = (bid & 7)*32 + (bid >> 3);
  int ks  = swz >> 6;                        // 0..3
  int rem = swz & 63;
  int b   = rem >> 3;
  int nt  = (rem >> 1) & 3;
  int mt  = rem & 1;

  int tid = threadIdx.x;
  int w = tid >> 6, lane = tid & 63, lg = lane >> 4, li = lane & 15;
  int wm = w >> 2, wn = w & 3;
  int sl = li & 7;

  const halfT* Ab = P16 + (size_t)b*M_*L_ + (size_t)mt*256*L_ + ks*1024;
  const halfT* Bb = qs16 + ((size_t)b*L_ + ks*1024)*D_ + nt*256;
  int krow = tid >> 3;                       // 0..63 (Bt k-position)
  int seg  = tid & 7;
  int pinv = ((krow & 3) << 4) | (krow >> 2); // qs16 source row for position krow
  int rs   = pinv & 7;

  f32x4 acc[8][4];
  #pragma unroll
  for (int i=0;i<8;++i)
    #pragma unroll
    for (int j=0;j<4;++j) acc[i][j] = (f32x4){0.f,0.f,0.f,0.f};

  half8 hx[4];

#define GLOADB_PV(kt_)                                                         \
  do {                                                                         \
    const halfT* rowp = Bb + (size_t)((kt_)*64 + pinv)*D_ + (seg >> 1)*64;     \
    _Pragma("unroll")                                                          \
    for (int j = 0; j < 4; ++j)                                                \
      hx[j] = *(const half8*)(rowp + ((((seg & 1)*4 + j) ^ rs) << 3));         \
  } while (0)

// 4 gload_lds per thread per tile (A-side vmcnt unit).
#define STAGEA_PV(nb_, kt_)                                                    \
  do {                                                                         \
    const halfT* a0 = Ab + (size_t)(kt_)*64 + (tid & 7)*8;                     \
    _Pragma("unroll")                                                          \
    for (int j = 0; j < 4; ++j)                                                \
      gload_lds16(a0 + (size_t)((tid >> 3) + j*64)*L_, &At[nb_][(tid + j*512)*8]); \
  } while (0)

#define WRITEB_PV(nb_)                                                         \
  do {                                                                         \
    _Pragma("unroll")                                                          \
    for (int i = 0; i < 32; ++i) {                                             \
      int n_ = seg*32 + i;                                                     \
      Bt[nb_][n_*64 + ((((krow >> 3) ^ SWZ(n_)) << 3)) + (krow & 7)] =         \
          hx[i >> 3][i & 7];                                                   \
    }                                                                          \
  } while (0)

#define COMPUTE_PV(nb_)                                                        \
  do {                                                                         \
    _Pragma("unroll")                                                          \
    for (int ksub = 0; ksub < 2; ++ksub) {                                     \
      int gx = ((ksub*4 + lg) ^ sl) << 3;                                      \
      half8 Af[8], Bf[4];                                                      \
      _Pragma("unroll")                                                        \
      for (int mf = 0; mf < 8; ++mf)                                           \
        Af[mf] = *(const half8*)&At[nb_][(wm*128 + mf*16 + li)*64 + gx];       \
      _Pragma("unroll")                                                        \
      for (int nf = 0; nf < 4; ++nf) {                                         \
        int n_ = wn*64 + nf*16 + li;                                           \
        Bf[nf] = *(const half8*)&Bt[nb_][n_*64 + (((ksub*4 + lg) ^ SWZ(n_)) << 3)]; \
      }                                                                        \
      _Pragma("unroll")                                                        \
      for (int mf = 0; mf < 8; ++mf)                                           \
        _Pragma("unroll")                                                      \
        for (int nf = 0; nf < 4; ++nf)                                         \
          acc[mf][nf] = __builtin_amdgcn_mfma_f32_16x16x32_f16(Af[mf], Bf[nf], acc[mf][nf], 0,0,0); \
    }                                                                          \
  } while (0)

  // Prologue: A tiles 0,1 in flight; B tile 0 written; hx <- tile 1.
  GLOADB_PV(0);
  STAGEA_PV(0, 0);
  STAGEA_PV(1, 1);
  WRITEB_PV(0);                              // compiler-counted wait for hx(0)
  GLOADB_PV(1);
  asm volatile("s_waitcnt vmcnt(8) lgkmcnt(0)" ::: "memory");   // A(0) landed; writes(0) done
  __builtin_amdgcn_sched_barrier(0);
  __builtin_amdgcn_s_barrier();

  for (int kt = 0; kt < 16; ++kt) {
    COMPUTE_PV(kt & 1);
    __builtin_amdgcn_s_barrier();            // B2: all reads of tile kt done
    if (kt + 1 < 16) WRITEB_PV((kt + 1) & 1);   // hx(kt+1) -> B-LDS (freed by B2 of kt-1)
    if (kt + 2 < 16) {
      GLOADB_PV(kt + 2);                     // hx <- tile kt+2
      STAGEA_PV(kt & 1, kt + 2);             // A tile kt+2 into freed buffer
      asm volatile("s_waitcnt vmcnt(8) lgkmcnt(0)" ::: "memory");  // A(kt+1) landed; writes visible
    } else {
      asm volatile("s_waitcnt vmcnt(0) lgkmcnt(0)" ::: "memory");
    }
    __builtin_amdgcn_sched_barrier(0);
    __builtin_amdgcn_s_barrier();            // B1
  }
#undef GLOADB_PV
#undef STAGEA_PV
#undef WRITEB_PV
#undef COMPUTE_PV

  halfT* Cb = rp16 + (size_t)ks*((size_t)B_*M_*D_) + (size_t)b*M_*D_;
  int cpbase = nt*256 + wn*64 + li*4;        // permuted col base for this lane
  #pragma unroll
  for (int mf = 0; mf < 8; ++mf) {
    #pragma unroll
    for (int r = 0; r < 4; ++r) {
      int row = mt*256 + wm*128 + mf*16 + lg*4 + r;
      half4_t hv;
      #pragma unroll
      for (int nf = 0; nf < 4; ++nf) hv[nf] = (halfT)acc[mf][nf][r];
      *(half4_t*)&Cb[(size_t)row*D_ + cpbase] = hv;
    }
  }
}

// ---------------- row softmax: 1 row per WAVE ----------------
// grid 1024 x 256 thr (4 waves = 4 rows). S16 read linear (permuted layout);
// per iteration i all lanes are in nt tile i: shift d_i = m_loc_i - M.
// P16 written at the SAME permuted positions, chunk-swizzled by row&7.
__global__ __launch_bounds__(256)
void softmax_rows(const halfT* __restrict__ S16, const float* __restrict__ mloc,
                  halfT* __restrict__ P, float* __restrict__ invl)
{
  int tid = threadIdx.x;
  int w = tid >> 6, lane = tid & 63;
  int row = blockIdx.x*4 + w;              // 0..4095 = b*512+m
  int b = row >> 9, m = row & 511;
  int rs  = row & 7;
  float mv = (lane < 16) ? mloc[((size_t)b*16 + lane)*M_ + m] : -3.0e38f;
  float M = mv;
  #pragma unroll
  for (int off = 1; off < 64; off <<= 1) M = fmaxf(M, __shfl_xor(M, off));

  const halfT* src = S16 + (size_t)row*L_;
  halfT* dst = P + (size_t)row*L_;
  float sum = 0.f;
  #pragma unroll
  for (int i = 0; i < 16; ++i) {
    float di = __shfl(mv, i) - M;
    half4_t s4 = *(const half4_t*)&src[(size_t)(i*64 + lane)*4];
    half4_t h;
    #pragma unroll
    for (int e = 0; e < 4; ++e) {
      float ev = __expf((float)s4[e] + di);
      sum += ev;
      h[e] = (halfT)ev;
    }
    int c = i*64 + lane;                   // permuted half4-chunk index (0..1023)
    int kt = c >> 4, g = (c >> 1) & 7, o = c & 1;
    *(half4_t*)&dst[kt*64 + ((g ^ rs) << 3) + o*4] = h;
  }
  #pragma unroll
  for (int off = 1; off < 64; off <<= 1) sum += __shfl_xor(sum, off);
  if (lane == 0) invl[row] = 1.0f / sum;
}

// ---------------- combine: out = invl * sum_ks rp16[ks] (permuted cols) ----------------
__global__ __launch_bounds__(256)
void combine_scale(const halfT* __restrict__ rp16, const float* __restrict__ invl,
                   float* __restrict__ out)
{
  int bm = blockIdx.x;                     // 0..4095
  int t = threadIdx.x;
  size_t off = (size_t)bm*D_ + t*4;
  f32x4 v = (f32x4){0.f,0.f,0.f,0.f};
  #pragma unroll
  for (int s = 0; s < 4; ++s) {
    half4_t h = *(const half4_t*)&rp16[(size_t)s*((size_t)B_*M_*D_) + off];
    #pragma unroll
    for (int j = 0; j < 4; ++j) v[j] += (float)h[j];
  }
  float sc = invl[bm];
  v *= sc;
  int W = (t >> 4) << 6;
  float* ob = out + (size_t)bm*D_;
  #pragma unroll
  for (int j = 0; j < 4; ++j)
    ob[W + j*16 + (t & 15)] = v[j];
}

// ---------------- fallback (tiny ws): correct, slow fp32 ----------------
__global__ void fallback_kernel(const float* __restrict__ qs,
                                const float* __restrict__ mem,
                                float* __restrict__ out)
{
  __shared__ float w_lds[4][4096];
  __shared__ float mem_s[4][1024];
  __shared__ float redb[256];
  int blk = blockIdx.x;
  int b = blk >> 7;
  int m0 = (blk & 127)*4;
  int tid = threadIdx.x;

  for (int i = tid; i < 4*1024; i += 256)
    mem_s[i>>10][i&1023] = mem[(size_t)(m0 + (i>>10))*D_ + (i&1023)];
  __syncthreads();

  float mx[4] = {-3e38f,-3e38f,-3e38f,-3e38f};
  for (int l = tid; l < L_; l += 256) {
    const float* qp = qs + ((size_t)b*L_ + l)*D_;
    float dot[4] = {0,0,0,0};
    for (int dd = 0; dd < D_; dd += 4) {
      f32x4 qv = *(const f32x4*)(qp + dd);
      #pragma unroll
      for (int mi=0; mi<4; ++mi)
        dot[mi] += qv[0]*mem_s[mi][dd] + qv[1]*mem_s[mi][dd+1]
                 + qv[2]*mem_s[mi][dd+2] + qv[3]*mem_s[mi][dd+3];
    }
    #pragma unroll
    for (int mi=0; mi<4; ++mi) { w_lds[mi][l] = dot[mi]; mx[mi] = fmaxf(mx[mi], dot[mi]); }
  }
  float Mv[4], Zv[4];
  for (int mi=0; mi<4; ++mi) {
    redb[tid] = mx[mi]; __syncthreads();
    for (int s=128; s>0; s>>=1) { if (tid<s) redb[tid]=fmaxf(redb[tid],redb[tid+s]); __syncthreads(); }
    Mv[mi] = redb[0]; __syncthreads();
  }
  float sm[4] = {0,0,0,0};
  for (int l = tid; l < L_; l += 256)
    #pragma unroll
    for (int mi=0; mi<4; ++mi) {
      float wv = __expf(w_lds[mi][l] - Mv[mi]);
      w_lds[mi][l] = wv; sm[mi] += wv;
    }
  for (int mi=0; mi<4; ++mi) {
    redb[tid] = sm[mi]; __syncthreads();
    for (int s=128; s>0; s>>=1) { if (tid<s) redb[tid]+=redb[tid+s]; __syncthreads(); }
    Zv[mi] = redb[0]; __syncthreads();
  }
  int d0 = tid*4;
  f32x4 a[4];
  #pragma unroll
  for (int mi=0;mi<4;++mi) a[mi] = (f32x4){0,0,0,0};
  for (int l = 0; l < L_; ++l) {
    f32x4 qv = *(const f32x4*)(qs + ((size_t)b*L_ + l)*D_ + d0);
    #pragma unroll
    for (int mi=0; mi<4; ++mi) a[mi] += qv * w_lds[mi][l];
  }
  #pragma unroll
  for (int mi=0; mi<4; ++mi) {
    float invz = 1.f/Zv[mi];
    #pragma unroll
    for (int c=0; c<4; ++c)
      out[((size_t)b*M_ + m0 + mi)*D_ + d0 + c] = a[mi][c]*invz;
  }
}

extern "C" void kernel_launch(void* const* d_in, const int* in_sizes, int n_in,
                              void* d_out, int out_size, void* d_ws, size_t ws_size,
                              hipStream_t stream) {
  const float* qs  = (const float*)d_in[0];
  const float* mem = (const float*)d_in[1];
  float* out = (float*)d_out;

  // tuple output: r [8*512*1024] then memory [512*1024]
  hipMemcpyAsync(out + (size_t)B_*M_*D_, mem, (size_t)M_*D_*sizeof(float),
                 hipMemcpyDeviceToDevice, stream);

  if (ws_size >= (size_t)WS_NEED) {
    char* base = (char*)d_ws;
    halfT* mem16 = (halfT*)(base + OFF_MEM16);
    halfT* qs16  = (halfT*)(base + OFF_QS16);
    halfT* S16   = (halfT*)(base + OFF_S);
    halfT* P16   = (halfT*)(base + OFF_P16);
    float* invl  = (float*)(base + OFF_INVL);
    float* mloc  = (float*)(base + OFF_MLOC);
    halfT* rp16  = (halfT*)(base + OFF_RP);    // overlays S16 (dead after softmax)

    prep_all<<<2304, 256, 0, stream>>>(qs, mem, qs16, mem16);
    gemm_qk<<<256, 512, 0, stream>>>(mem16, qs16, S16, mloc);
    softmax_rows<<<1024, 256, 0, stream>>>(S16, mloc, P16, invl);
    gemm_pv<<<256, 512, 0, stream>>>(P16, qs16, rp16);
    combine_scale<<<4096, 256, 0, stream>>>(rp16, invl, out);
  } else {
    fallback_kernel<<<1024, 256, 0, stream>>>(qs, mem, out);
  }
}